// Round 2
// baseline (871.983 us; speedup 1.0000x reference)
//
#include <hip/hip_runtime.h>
#include <math.h>

#define N_NODES 10000
#define N_EDGES 160000
#define FDIM    512
#define DOUT    256
#define NCAT    768     // [W0-W2 | W1 | W2]

#define EDGE_BLOCKS 625   // 160000 / 256
#define XB_BLOCKS   5000  // 10000*512 / 4 / 256
#define W_BLOCKS    224   // 64 (W1t) + 64 (W2t) + 96 (Wcatt)
#define PRE1_TASKS  (EDGE_BLOCKS + XB_BLOCKS + W_BLOCKS)
#define SCAN_BLOCKS 40
#define FILL_BLOCKS 625
#define NV_SAGG8    (313 * 8)
#define NV_SAGG4    (313 * 4)
#define G_GEMM1     640   // 8*ceil(157/8)*4
#define G_GEMM3     960   // 8*ceil(157/8)*6

typedef unsigned short ushort_t;
typedef unsigned int   uint_t;
typedef __attribute__((ext_vector_type(8))) short bf16x8;
typedef __attribute__((ext_vector_type(4))) float f32x4;

// ---------------------------------------------------------------------------
// helpers
// ---------------------------------------------------------------------------
__device__ inline ushort_t f2bf(float f) {
    uint_t u = __float_as_uint(f);
    u += 0x7fffu + ((u >> 16) & 1u);        // round-to-nearest-even
    return (ushort_t)(u >> 16);
}
__device__ inline void bf2f8(uint4 u, float* v) {
    v[0] = __uint_as_float(u.x << 16); v[1] = __uint_as_float(u.x & 0xffff0000u);
    v[2] = __uint_as_float(u.y << 16); v[3] = __uint_as_float(u.y & 0xffff0000u);
    v[4] = __uint_as_float(u.z << 16); v[5] = __uint_as_float(u.z & 0xffff0000u);
    v[6] = __uint_as_float(u.w << 16); v[7] = __uint_as_float(u.w & 0xffff0000u);
}
__device__ inline uint4 f2bf8v(const float* v) {
    uint4 u;
    u.x = (uint_t)f2bf(v[0]) | ((uint_t)f2bf(v[1]) << 16);
    u.y = (uint_t)f2bf(v[2]) | ((uint_t)f2bf(v[3]) << 16);
    u.z = (uint_t)f2bf(v[4]) | ((uint_t)f2bf(v[5]) << 16);
    u.w = (uint_t)f2bf(v[6]) | ((uint_t)f2bf(v[7]) << 16);
    return u;
}
__device__ inline void gld_lds16(const ushort_t* g, ushort_t* l) {
    __builtin_amdgcn_global_load_lds(
        (const __attribute__((address_space(1))) unsigned int*)g,
        (__attribute__((address_space(3))) unsigned int*)l,
        16, 0, 0);
}

// ---------------------------------------------------------------------------
// Persistent mega-kernel. All 11 pipeline phases in ONE dispatch; device-wide
// ticket barriers between phases. Theory (R2): ~130us of the 240us total was
// inter-dispatch serialization (12 dependent dispatches; identifiable work
// sums to ~100us). Co-residency: grid sized from
// hipOccupancyMaxActiveBlocksPerMultiprocessor (exact, same calc the HW
// uses), so the ticket barrier cannot deadlock. Cross-XCD coherence: agent
// __threadfence on release AND acquire side of each barrier (emits
// buffer_wbl2/inv sc1 on gfx950) — same cache ops the CP performs at every
// kernel boundary today, so no added traffic vs the multi-kernel version.
// Barrier counter is monotonic (ticket): no reset race; memset re-zeros it
// every replay so workspace poison can't skew generation arithmetic.
// ---------------------------------------------------------------------------
struct MegaParams {
    const float* x; const int* row; const int* col; const float* ew;
    const float* W1; const float* b1; const float* W2; const float* b2;
    const float* Wc; const float* bc; float* out;
    ushort_t* xb; ushort_t* bufA; ushort_t* bufB; ushort_t* Y; ushort_t* P;
    ushort_t* W1t; ushort_t* W2t; ushort_t* Wcatt;
    float* deg_g; float* deg_c; int* counts; int* fillb; unsigned* bar;
    float* dinv_g; float* dinv_c; int* rp; int* part;
    int2* eg; int2* ec;
};

union SMem {
    float tile[64][65];                                   // 16640 B (pre1 W-transpose)
    struct { ushort_t As[64 * 32]; ushort_t Bs[128 * 32]; } g;  // 12 KB (gemm)
    int scan[256];                                        // scan1
    struct { int soff[64]; int stot; } s23;               // scan23
};

__device__ inline void gsync(unsigned* bar, int nb) {
    __syncthreads();                        // all block stores issued (waitcnt vmcnt(0))
    if (threadIdx.x == 0) {
        __threadfence();                    // release: flush this XCD's L2
        unsigned old = atomicAdd(bar, 1u);
        unsigned target = (old / (unsigned)nb + 1u) * (unsigned)nb;
        while (__hip_atomic_load(bar, __ATOMIC_RELAXED, __HIP_MEMORY_SCOPE_AGENT) < target)
            __builtin_amdgcn_s_sleep(2);
        __threadfence();                    // acquire: invalidate stale L1/L2
    }
    __syncthreads();
}

// --- phase 1: edge-degree atomics + x->bf16 + weight transposes ------------
__device__ void d_pre1(const MegaParams& p, int b, int tid, SMem& sm) {
    if (b < EDGE_BLOCKS) {
        int e = b * 256 + tid;
        if (e < N_EDGES) {
            int r = p.row[e], c = p.col[e];
            float wv = p.ew[e];
            atomicAdd(&p.deg_g[c], wv);
            if (r != c) atomicAdd(&p.deg_c[r], wv);
            atomicAdd(&p.counts[c], 1);
        }
        return;
    }
    b -= EDGE_BLOCKS;
    if (b < XB_BLOCKS) {
        int t = b * 256 + tid;
        float4 v = *(const float4*)(p.x + (size_t)t * 4);
        uint2 q;
        q.x = (uint_t)f2bf(v.x) | ((uint_t)f2bf(v.y) << 16);
        q.y = (uint_t)f2bf(v.z) | ((uint_t)f2bf(v.w) << 16);
        *(uint2*)(p.xb + (size_t)t * 4) = q;
        return;
    }
    b -= XB_BLOCKS;
    const float* src; const float* src2 = nullptr;
    ushort_t* dst; int kt, ntG, srcld;
    if (b < 64) {                       // W1 [512][512]
        kt = b >> 3; ntG = b & 7; srcld = FDIM;
        src = p.W1 + (size_t)(kt * 64) * FDIM + ntG * 64;
        dst = p.W1t;
    } else if (b < 128) {               // W2
        int bb = b - 64;
        kt = bb >> 3; ntG = bb & 7; srcld = FDIM;
        src = p.W2 + (size_t)(kt * 64) * FDIM + ntG * 64;
        dst = p.W2t;
    } else {                            // Wcat: ntG in [0,12), kt in [0,8)
        int bb = b - 128;
        ntG = bb / 8; kt = bb % 8; srcld = DOUT;
        int s = ntG >> 2;               // section 0,1,2
        int nl = (ntG & 3) * 64;        // col within 256
        if (s == 0) {                   // W0 - W2
            src  = p.Wc + (size_t)(kt * 64) * DOUT + nl;
            src2 = p.Wc + (size_t)2 * FDIM * DOUT + (size_t)(kt * 64) * DOUT + nl;
        } else if (s == 1) {            // W1 (Cheb k=1)
            src  = p.Wc + (size_t)1 * FDIM * DOUT + (size_t)(kt * 64) * DOUT + nl;
        } else {                        // W2
            src  = p.Wc + (size_t)2 * FDIM * DOUT + (size_t)(kt * 64) * DOUT + nl;
        }
        dst = p.Wcatt;
    }
    __syncthreads();    // tile may still be read by this block's previous W task
    {
        int r = tid >> 2, c0 = (tid & 3) * 16;
        const float* sp = src + (size_t)r * srcld + c0;
#pragma unroll
        for (int q = 0; q < 4; ++q) {
            float4 a = *(const float4*)(sp + q * 4);
            if (src2) {
                float4 bsub = *(const float4*)(src2 + (size_t)r * srcld + c0 + q * 4);
                a.x -= bsub.x; a.y -= bsub.y; a.z -= bsub.z; a.w -= bsub.w;
            }
            sm.tile[r][c0 + q * 4 + 0] = a.x;
            sm.tile[r][c0 + q * 4 + 1] = a.y;
            sm.tile[r][c0 + q * 4 + 2] = a.z;
            sm.tile[r][c0 + q * 4 + 3] = a.w;
        }
    }
    __syncthreads();
    {
        int n = tid >> 2, k0 = (tid & 3) * 16;
        float v[16];
#pragma unroll
        for (int i = 0; i < 16; ++i) v[i] = sm.tile[k0 + i][n];
        uint4 u0 = f2bf8v(v);
        uint4 u1 = f2bf8v(v + 8);
        ushort_t* dp = dst + (size_t)(ntG * 64 + n) * FDIM + kt * 64 + k0;
        *(uint4*)dp = u0;
        *(uint4*)(dp + 8) = u1;
    }
}

// --- phase 2: dinv + block-local scan --------------------------------------
__device__ void d_scan1(const MegaParams& p, int vb, int tid, SMem& sm) {
    int i = vb * 256 + tid;
    if (i < N_NODES) {
        p.dinv_g[i] = rsqrtf(p.deg_g[i] + 1.0f);
        float d = p.deg_c[i];
        p.dinv_c[i] = d > 0.f ? rsqrtf(d) : 0.f;
    }
    int v = (i < N_NODES) ? p.counts[i] : 0;
    sm.scan[tid] = v;
    __syncthreads();
    for (int o = 1; o < 256; o <<= 1) {
        int t = (tid >= o) ? sm.scan[tid - o] : 0;
        __syncthreads();
        sm.scan[tid] += t;
        __syncthreads();
    }
    if (i < N_NODES) p.rp[i] = sm.scan[tid] - v;
    if (tid == 255) p.part[vb] = sm.scan[255];
}

// --- phase 3: finalize scan (every vb redundantly wave-scans 40 partials) --
__device__ void d_scan23(const MegaParams& p, int vb, int tid, SMem& sm) {
    if (tid < 64) {
        int v = (tid < SCAN_BLOCKS) ? p.part[tid] : 0;
        int x = v;
        for (int o = 1; o < 64; o <<= 1) {
            int y = __shfl_up(x, o, 64);
            if (tid >= o) x += y;
        }
        sm.s23.soff[tid] = x - v;
        if (tid == 63) sm.s23.stot = x;
    }
    __syncthreads();
    int i = vb * 256 + tid;
    if (i < N_NODES) p.rp[i] += sm.s23.soff[vb];
    if (vb == 0 && tid == 0) p.rp[N_NODES] = sm.s23.stot;
}

// --- phase 4: CSR fill; n_c stored NEGATED so lhat is a plain sum ----------
__device__ void d_fill(const MegaParams& p, int vb, int tid) {
    int e = vb * 256 + tid;
    if (e >= N_EDGES) return;
    int r = p.row[e], c = p.col[e];
    float wv = p.ew[e];
    float ng = p.dinv_g[r] * wv * p.dinv_g[c];
    float w0 = (r == c) ? 0.f : wv;
    float nc = -(p.dinv_c[r] * w0 * p.dinv_c[c]);
    int pos = p.rp[c] + atomicAdd(&p.fillb[c], 1);
    p.eg[pos] = make_int2(r, __float_as_int(ng));
    p.ec[pos] = make_int2(r, __float_as_int(nc));
}

// --- GEMM phase: staged bf16 MFMA, 64x128 tile, BK=32, 4 waves 2x2 ---------
__device__ void d_gemm(SMem& sm, const ushort_t* __restrict__ A,
                       const ushort_t* __restrict__ Bt, int N,
                       int nbx, int nby, int vb, int tid,
                       ushort_t* __restrict__ outB)
{
    int j = vb & 7, t = vb >> 3;        // XCD swizzle (grid multiple of 8)
    int by = t % nby;
    int bx = (t / nby) * 8 + j;
    if (bx >= nbx) return;              // uniform per block — safe

    const int w    = tid >> 6;
    const int lane = tid & 63;
    const int l15  = lane & 15;
    const int quad = lane >> 4;
    const int bm = bx * 64, bn = by * 128;
    const int wm = (w & 1) * 32;
    const int wn = (w >> 1) * 64;

    const int sr = lane >> 2;           // 0..15
    const int sc = (lane & 3) * 8;      // 0,8,16,24
    int arow = min(bm + w * 16 + sr, N_NODES - 1);
    const ushort_t* ag = A + (size_t)arow * FDIM + sc;
    ushort_t* al = sm.g.As + (w * 16 + sr) * 32 + sc;
    const ushort_t* bg0 = Bt + (size_t)(bn + w * 32 + sr) * FDIM + sc;
    const ushort_t* bg1 = bg0 + (size_t)16 * FDIM;
    ushort_t* bl0 = sm.g.Bs + (w * 32 + sr) * 32 + sc;
    ushort_t* bl1 = bl0 + 16 * 32;

    f32x4 acc[2][4] = {};

    for (int k0 = 0; k0 < FDIM; k0 += 32) {
        __syncthreads();
        gld_lds16(ag + k0, al);
        gld_lds16(bg0 + k0, bl0);
        gld_lds16(bg1 + k0, bl1);
        __syncthreads();
        bf16x8 af[2], bfr[4];
#pragma unroll
        for (int i = 0; i < 2; ++i)
            af[i] = *(const bf16x8*)(sm.g.As + (wm + i * 16 + l15) * 32 + quad * 8);
#pragma unroll
        for (int jj = 0; jj < 4; ++jj)
            bfr[jj] = *(const bf16x8*)(sm.g.Bs + (wn + jj * 16 + l15) * 32 + quad * 8);
#pragma unroll
        for (int i = 0; i < 2; ++i)
#pragma unroll
            for (int jj = 0; jj < 4; ++jj)
                acc[i][jj] = __builtin_amdgcn_mfma_f32_16x16x32_bf16(af[i], bfr[jj], acc[i][jj], 0, 0, 0);
    }

    // C/D layout: col = lane&15, row = quad*4 + reg (m89-verified)
#pragma unroll
    for (int i = 0; i < 2; ++i) {
        int rowb = bm + wm + i * 16 + quad * 4;
#pragma unroll
        for (int jj = 0; jj < 4; ++jj) {
            int col = bn + wn + jj * 16 + l15;
#pragma unroll
            for (int r = 0; r < 4; ++r) {
                int rr = rowb + r;
                if (rr < N_NODES)
                    outB[(size_t)rr * N + col] = f2bf(acc[i][jj][r]);
            }
        }
    }
}

// --- sagg phase: XCD-feature-sliced aggregation (round-0 structure) --------
// NOTE: no barriers inside; c>=N guard must NOT return past a barrier —
// body is barrier-free so plain skip is safe.
template<int SL>
__device__ void d_sagg(const MegaParams& p, int vb, int tid,
    const ushort_t* __restrict__ h, int hs, int hoff,
    const int2* __restrict__ er, const float* __restrict__ dinv_g,
    const ushort_t* __restrict__ other, int os, int ooff, float sB,
    const float* __restrict__ bias, float sA,
    ushort_t* __restrict__ outB, float* __restrict__ outF, int outs, int celu)
{
    const int sl = vb % SL;
    const int c  = (vb / SL) * 32 + (tid >> 3);
    if (c >= N_NODES) return;
    const int f = sl * 64 + ((tid & 7) << 3);
    const ushort_t* hp = h + hoff + f;

    float acc[8] = {0.f, 0.f, 0.f, 0.f, 0.f, 0.f, 0.f, 0.f};
    int e = p.rp[c];
    const int e1 = p.rp[c + 1];
    for (; e + 4 <= e1; e += 4) {
        int2 p0 = er[e], p1 = er[e + 1], p2 = er[e + 2], p3 = er[e + 3];
        uint4 u0 = *(const uint4*)(hp + (size_t)p0.x * hs);
        uint4 u1 = *(const uint4*)(hp + (size_t)p1.x * hs);
        uint4 u2 = *(const uint4*)(hp + (size_t)p2.x * hs);
        uint4 u3 = *(const uint4*)(hp + (size_t)p3.x * hs);
        float n0 = __int_as_float(p0.y), n1 = __int_as_float(p1.y);
        float n2 = __int_as_float(p2.y), n3 = __int_as_float(p3.y);
        float v0[8], v1[8], v2[8], v3[8];
        bf2f8(u0, v0); bf2f8(u1, v1); bf2f8(u2, v2); bf2f8(u3, v3);
#pragma unroll
        for (int i = 0; i < 8; ++i) {
            acc[i] = fmaf(n0, v0[i], acc[i]);
            acc[i] = fmaf(n1, v1[i], acc[i]);
            acc[i] = fmaf(n2, v2[i], acc[i]);
            acc[i] = fmaf(n3, v3[i], acc[i]);
        }
    }
    for (; e < e1; ++e) {
        int2 pe = er[e];
        uint4 u = *(const uint4*)(hp + (size_t)pe.x * hs);
        float nv = __int_as_float(pe.y);
        float v[8]; bf2f8(u, v);
#pragma unroll
        for (int i = 0; i < 8; ++i) acc[i] = fmaf(nv, v[i], acc[i]);
    }

    if (dinv_g) {                       // GCN self-loop term
        float dv = dinv_g[c];
        float d2 = dv * dv;
        uint4 u = *(const uint4*)(hp + (size_t)c * hs);
        float v[8]; bf2f8(u, v);
#pragma unroll
        for (int i = 0; i < 8; ++i) acc[i] = fmaf(d2, v[i], acc[i]);
    }
    float r[8];
#pragma unroll
    for (int i = 0; i < 8; ++i) r[i] = sA * acc[i];
    if (other) {
        uint4 u = *(const uint4*)(other + (size_t)c * os + ooff + f);
        float o[8]; bf2f8(u, o);
#pragma unroll
        for (int i = 0; i < 8; ++i) r[i] = fmaf(sB, o[i], r[i]);
    }
    if (bias) {
#pragma unroll
        for (int i = 0; i < 8; ++i) r[i] += bias[f + i];
    }
    if (celu) {
#pragma unroll
        for (int i = 0; i < 8; ++i) r[i] = r[i] > 0.f ? r[i] : expm1f(r[i]);
    }
    if (outF) {
        float* op = outF + (size_t)c * outs + f;
        *(float4*)op       = make_float4(r[0], r[1], r[2], r[3]);
        *(float4*)(op + 4) = make_float4(r[4], r[5], r[6], r[7]);
    } else {
        *(uint4*)(outB + (size_t)c * outs + f) = f2bf8v(r);
    }
}

// ---------------------------------------------------------------------------
__global__ __launch_bounds__(256, 3) void k_mega(MegaParams p) {
    __shared__ SMem sm;
    const int tid = threadIdx.x;
    const int b0  = blockIdx.x;
    const int NB  = gridDim.x;

    for (int vb = b0; vb < PRE1_TASKS; vb += NB) d_pre1(p, vb, tid, sm);
    gsync(p.bar, NB);
    for (int vb = b0; vb < SCAN_BLOCKS; vb += NB) d_scan1(p, vb, tid, sm);
    gsync(p.bar, NB);
    for (int vb = b0; vb < SCAN_BLOCKS; vb += NB) d_scan23(p, vb, tid, sm);
    gsync(p.bar, NB);
    for (int vb = b0; vb < FILL_BLOCKS; vb += NB) d_fill(p, vb, tid);
    gsync(p.bar, NB);
    // GCN layer 1: h1 = x@W1 ; h1a = celu(agg(h1)+b1)
    for (int vb = b0; vb < G_GEMM1; vb += NB)
        d_gemm(sm, p.xb, p.W1t, FDIM, 157, 4, vb, tid, p.bufA);
    gsync(p.bar, NB);
    for (int vb = b0; vb < NV_SAGG8; vb += NB)
        d_sagg<8>(p, vb, tid, p.bufA, FDIM, 0, p.eg, p.dinv_g,
                  (const ushort_t*)nullptr, 0, 0, 0.f, p.b1, 1.f,
                  p.bufB, (float*)nullptr, FDIM, 1);
    gsync(p.bar, NB);
    // GCN layer 2
    for (int vb = b0; vb < G_GEMM1; vb += NB)
        d_gemm(sm, p.bufB, p.W2t, FDIM, 157, 4, vb, tid, p.bufA);
    gsync(p.bar, NB);
    for (int vb = b0; vb < NV_SAGG8; vb += NB)
        d_sagg<8>(p, vb, tid, p.bufA, FDIM, 0, p.eg, p.dinv_g,
                  (const ushort_t*)nullptr, 0, 0, 0.f, p.b2, 1.f,
                  p.bufB, (float*)nullptr, FDIM, 1);
    gsync(p.bar, NB);
    // Cheb (commuted): Y = T0 @ [W0-W2 | W1 | W2]
    for (int vb = b0; vb < G_GEMM3; vb += NB)
        d_gemm(sm, p.bufB, p.Wcatt, NCAT, 157, 6, vb, tid, p.Y);
    gsync(p.bar, NB);
    // P = Y1 + 2*Lhat(Y2)
    for (int vb = b0; vb < NV_SAGG4; vb += NB)
        d_sagg<4>(p, vb, tid, p.Y, NCAT, 2 * DOUT, p.ec,
                  (const float*)nullptr, p.Y, NCAT, DOUT, 1.f,
                  (const float*)nullptr, 2.f,
                  p.P, (float*)nullptr, DOUT, 0);
    gsync(p.bar, NB);
    // out = celu(Y0 + Lhat(P) + bc)   (fp32 straight to d_out)
    for (int vb = b0; vb < NV_SAGG4; vb += NB)
        d_sagg<4>(p, vb, tid, p.P, DOUT, 0, p.ec,
                  (const float*)nullptr, p.Y, NCAT, 0, 1.f,
                  p.bc, 1.f,
                  (ushort_t*)nullptr, p.out, DOUT, 1);
}

// ---------------------------------------------------------------------------

extern "C" void kernel_launch(void* const* d_in, const int* in_sizes, int n_in,
                              void* d_out, int out_size, void* d_ws, size_t ws_size,
                              hipStream_t stream) {
    const float* x  = (const float*)d_in[0];
    const int*   ei = (const int*)d_in[1];
    const float* ew = (const float*)d_in[2];
    const float* W1 = (const float*)d_in[3];
    const float* b1 = (const float*)d_in[4];
    const float* W2 = (const float*)d_in[5];
    const float* b2 = (const float*)d_in[6];
    const float* Wc = (const float*)d_in[7];
    const float* bc = (const float*)d_in[8];
    float* out = (float*)d_out;

    char* ws = (char*)d_ws;
    size_t off = 0;
    auto alloc = [&](size_t bytes) -> void* {
        void* p = ws + off;
        off += (bytes + 255) & ~(size_t)255;
        return p;
    };
    MegaParams P;
    P.x = x; P.row = ei; P.col = ei + N_EDGES; P.ew = ew;
    P.W1 = W1; P.b1 = b1; P.W2 = W2; P.b2 = b2; P.Wc = Wc; P.bc = bc;
    P.out = out;

    P.xb    = (ushort_t*)alloc((size_t)N_NODES * FDIM * 2);
    P.bufA  = (ushort_t*)alloc((size_t)N_NODES * FDIM * 2);   // h1 / h2
    P.bufB  = (ushort_t*)alloc((size_t)N_NODES * FDIM * 2);   // h1a / T0
    P.Y     = (ushort_t*)alloc((size_t)N_NODES * NCAT * 2);   // [Y0|Y1|Y2]
    P.P     = (ushort_t*)alloc((size_t)N_NODES * DOUT * 2);
    P.W1t   = (ushort_t*)alloc((size_t)FDIM * FDIM * 2);
    P.W2t   = (ushort_t*)alloc((size_t)FDIM * FDIM * 2);
    P.Wcatt = (ushort_t*)alloc((size_t)NCAT * FDIM * 2);
    size_t zs = off;
    P.deg_g  = (float*)alloc((size_t)N_NODES * 4);
    P.deg_c  = (float*)alloc((size_t)N_NODES * 4);
    P.counts = (int*)alloc((size_t)N_NODES * 4);
    P.fillb  = (int*)alloc((size_t)N_NODES * 4);
    P.bar    = (unsigned*)alloc(256);
    size_t ze = off;
    P.dinv_g = (float*)alloc((size_t)N_NODES * 4);
    P.dinv_c = (float*)alloc((size_t)N_NODES * 4);
    P.rp     = (int*)alloc((size_t)(N_NODES + 1) * 4);
    P.part   = (int*)alloc(64 * 4);
    P.eg     = (int2*)alloc((size_t)N_EDGES * 8);
    P.ec     = (int2*)alloc((size_t)N_EDGES * 8);

    // Grid: all blocks must be co-resident for the ticket barrier. Query the
    // exact occupancy for this kernel (accounts for final VGPR/LDS), size
    // grid = occ * 256 CUs, cap 1024, keep multiple of 8 for XCD swizzle.
    static int g_grid = 0;
    if (g_grid == 0) {
        int occ = 0;
        (void)hipOccupancyMaxActiveBlocksPerMultiprocessor(&occ, k_mega, 256, 0);
        if (occ < 1) occ = 1;
        long g = (long)occ * 256;
        if (g > 1024) g = 1024;
        g_grid = (int)g;
    }

    hipMemsetAsync(ws + zs, 0, ze - zs, stream);   // deg/counts/fill + barrier
    k_mega<<<g_grid, 256, 0, stream>>>(P);
}

// Round 3
// 252.168 us; speedup vs baseline: 3.4579x; 3.4579x over previous
//
#include <hip/hip_runtime.h>
#include <math.h>

#define N_NODES 10000
#define N_EDGES 160000
#define FDIM    512
#define DOUT    256
#define NCAT    768     // [W0-W2 | W1 | W2]

typedef unsigned short ushort_t;
typedef unsigned int   uint_t;
typedef __attribute__((ext_vector_type(8))) short bf16x8;
typedef __attribute__((ext_vector_type(4))) float f32x4;

// ---------------------------------------------------------------------------
// helpers
// ---------------------------------------------------------------------------
__device__ inline ushort_t f2bf(float f) {
    uint_t u = __float_as_uint(f);
    u += 0x7fffu + ((u >> 16) & 1u);        // round-to-nearest-even
    return (ushort_t)(u >> 16);
}
__device__ inline void bf2f8(uint4 u, float* v) {
    v[0] = __uint_as_float(u.x << 16); v[1] = __uint_as_float(u.x & 0xffff0000u);
    v[2] = __uint_as_float(u.y << 16); v[3] = __uint_as_float(u.y & 0xffff0000u);
    v[4] = __uint_as_float(u.z << 16); v[5] = __uint_as_float(u.z & 0xffff0000u);
    v[6] = __uint_as_float(u.w << 16); v[7] = __uint_as_float(u.w & 0xffff0000u);
}
__device__ inline uint4 f2bf8v(const float* v) {
    uint4 u;
    u.x = (uint_t)f2bf(v[0]) | ((uint_t)f2bf(v[1]) << 16);
    u.y = (uint_t)f2bf(v[2]) | ((uint_t)f2bf(v[3]) << 16);
    u.z = (uint_t)f2bf(v[4]) | ((uint_t)f2bf(v[5]) << 16);
    u.w = (uint_t)f2bf(v[6]) | ((uint_t)f2bf(v[7]) << 16);
    return u;
}
__device__ inline void gld_lds16(const ushort_t* g, ushort_t* l) {
    __builtin_amdgcn_global_load_lds(
        (const __attribute__((address_space(1))) unsigned int*)g,
        (__attribute__((address_space(3))) unsigned int*)l,
        16, 0, 0);
}

// ---------------------------------------------------------------------------
// Merged preprocessing stage 1 + conversions.
// Blocks [0,EDGE_BLOCKS): edge degrees/counts (atomics).
// Blocks [EDGE_BLOCKS, +5000): x -> bf16 (4 floats/thread, vectorized).
// Then 64 tiles W1^T, 64 tiles W2^T, 96 tiles Wcat^T where
// Wcat = [W0-W2 | W1 | W2] (512x768), stored transposed [768][512].
// ---------------------------------------------------------------------------
#define EDGE_BLOCKS 625   // 160000 / 256
#define XB_BLOCKS   5000  // 10000*512 / 4 / 256

__global__ __launch_bounds__(256) void k_pre1(
    const int* __restrict__ row, const int* __restrict__ col,
    const float* __restrict__ w,
    float* deg_g, float* deg_c, int* counts,
    const float* __restrict__ x,  ushort_t* __restrict__ xb,
    const float* __restrict__ W1, ushort_t* __restrict__ W1t,
    const float* __restrict__ W2, ushort_t* __restrict__ W2t,
    const float* __restrict__ Wc, ushort_t* __restrict__ Wcatt)
{
    __shared__ float tile[64][65];
    int b = blockIdx.x;
    int tid = threadIdx.x;
    if (b < EDGE_BLOCKS) {
        int e = b * 256 + tid;
        if (e < N_EDGES) {
            int r = row[e], c = col[e];
            float wv = w[e];
            atomicAdd(&deg_g[c], wv);
            if (r != c) atomicAdd(&deg_c[r], wv);
            atomicAdd(&counts[c], 1);
        }
        return;
    }
    b -= EDGE_BLOCKS;
    if (b < XB_BLOCKS) {
        int t = b * 256 + tid;
        float4 v = *(const float4*)(x + (size_t)t * 4);
        uint2 p;
        p.x = (uint_t)f2bf(v.x) | ((uint_t)f2bf(v.y) << 16);
        p.y = (uint_t)f2bf(v.z) | ((uint_t)f2bf(v.w) << 16);
        *(uint2*)(xb + (size_t)t * 4) = p;
        return;
    }
    b -= XB_BLOCKS;
    const float* src; const float* src2 = nullptr;
    ushort_t* dst; int kt, ntG, srcld;
    if (b < 64) {                       // W1 [512][512]
        kt = b >> 3; ntG = b & 7; srcld = FDIM;
        src = W1 + (size_t)(kt * 64) * FDIM + ntG * 64;
        dst = W1t;
    } else if (b < 128) {               // W2
        int bb = b - 64;
        kt = bb >> 3; ntG = bb & 7; srcld = FDIM;
        src = W2 + (size_t)(kt * 64) * FDIM + ntG * 64;
        dst = W2t;
    } else {                            // Wcat: ntG in [0,12), kt in [0,8)
        int bb = b - 128;
        ntG = bb / 8; kt = bb % 8; srcld = DOUT;
        int s = ntG >> 2;               // section 0,1,2
        int nl = (ntG & 3) * 64;        // col within 256
        if (s == 0) {                   // W0 - W2
            src  = Wc + (size_t)(kt * 64) * DOUT + nl;
            src2 = Wc + (size_t)2 * FDIM * DOUT + (size_t)(kt * 64) * DOUT + nl;
        } else if (s == 1) {            // W1 (Cheb k=1)
            src  = Wc + (size_t)1 * FDIM * DOUT + (size_t)(kt * 64) * DOUT + nl;
        } else {                        // W2
            src  = Wc + (size_t)2 * FDIM * DOUT + (size_t)(kt * 64) * DOUT + nl;
        }
        dst = Wcatt;
    }
    // load phase: thread (r = tid>>2, c0 = (tid&3)*16) loads 16 floats
    {
        int r = tid >> 2, c0 = (tid & 3) * 16;
        const float* sp = src + (size_t)r * srcld + c0;
#pragma unroll
        for (int q = 0; q < 4; ++q) {
            float4 a = *(const float4*)(sp + q * 4);
            if (src2) {
                float4 bsub = *(const float4*)(src2 + (size_t)r * srcld + c0 + q * 4);
                a.x -= bsub.x; a.y -= bsub.y; a.z -= bsub.z; a.w -= bsub.w;
            }
            tile[r][c0 + q * 4 + 0] = a.x;
            tile[r][c0 + q * 4 + 1] = a.y;
            tile[r][c0 + q * 4 + 2] = a.z;
            tile[r][c0 + q * 4 + 3] = a.w;
        }
    }
    __syncthreads();
    // store phase: thread (n = tid>>2, k0 = (tid&3)*16) writes 16 bf16 (32 B)
    {
        int n = tid >> 2, k0 = (tid & 3) * 16;
        float v[16];
#pragma unroll
        for (int i = 0; i < 16; ++i) v[i] = tile[k0 + i][n];
        uint4 u0 = f2bf8v(v);
        uint4 u1 = f2bf8v(v + 8);
        ushort_t* dp = dst + (size_t)(ntG * 64 + n) * FDIM + kt * 64 + k0;
        *(uint4*)dp = u0;
        *(uint4*)(dp + 8) = u1;
    }
}

__global__ __launch_bounds__(256) void k_dinv_scan1(
    const float* __restrict__ deg_g, const float* __restrict__ deg_c,
    float* __restrict__ dinv_g, float* __restrict__ dinv_c,
    const int* __restrict__ counts, int* __restrict__ rp,
    int* __restrict__ part, int n)
{
    __shared__ int s[256];
    int tid = threadIdx.x;
    int i = blockIdx.x * 256 + tid;
    if (i < n) {
        dinv_g[i] = rsqrtf(deg_g[i] + 1.0f);
        float d = deg_c[i];
        dinv_c[i] = d > 0.f ? rsqrtf(d) : 0.f;
    }
    int v = (i < n) ? counts[i] : 0;
    s[tid] = v;
    __syncthreads();
    for (int o = 1; o < 256; o <<= 1) {
        int t = (tid >= o) ? s[tid - o] : 0;
        __syncthreads();
        s[tid] += t;
        __syncthreads();
    }
    if (i < n) rp[i] = s[tid] - v;
    if (tid == 255) part[blockIdx.x] = s[255];
}

// fused scan2+scan3: every block redundantly wave-scans the <=64 partials
__global__ __launch_bounds__(256) void k_scan23(int* __restrict__ rp,
                                                const int* __restrict__ part,
                                                int nb, int n) {
    __shared__ int soff[64];
    __shared__ int stot;
    int tid = threadIdx.x;
    if (tid < 64) {
        int v = (tid < nb) ? part[tid] : 0;
        int x = v;
        for (int o = 1; o < 64; o <<= 1) {
            int y = __shfl_up(x, o, 64);
            if (tid >= o) x += y;
        }
        soff[tid] = x - v;
        if (tid == 63) stot = x;
    }
    __syncthreads();
    int i = blockIdx.x * 256 + tid;
    if (i < n) rp[i] += soff[blockIdx.x];
    if (blockIdx.x == 0 && tid == 0) rp[n] = stot;
}

// edge records (src, norm) 8B; n_c stored NEGATED so lhat is a plain sum
__global__ void k_fill(const int* __restrict__ row, const int* __restrict__ col,
                       const float* __restrict__ w,
                       const float* __restrict__ dinv_g, const float* __restrict__ dinv_c,
                       const int* __restrict__ rp, int* __restrict__ fill,
                       int2* __restrict__ eg, int2* __restrict__ ec, int E) {
    int e = blockIdx.x * blockDim.x + threadIdx.x;
    if (e >= E) return;
    int r = row[e], c = col[e];
    float wv = w[e];
    float ng = dinv_g[r] * wv * dinv_g[c];
    float w0 = (r == c) ? 0.f : wv;
    float nc = -(dinv_c[r] * w0 * dinv_c[c]);
    int pos = rp[c] + atomicAdd(&fill[c], 1);
    eg[pos] = make_int2(r, __float_as_int(ng));
    ec[pos] = make_int2(r, __float_as_int(nc));
}

// ---------------------------------------------------------------------------
// Staged bf16 MFMA GEMM (m97 structure). 64x128 tile, BK=32, 256 thr =
// 4 waves 2x2; wave tile 32x64 -> 2x4 MFMA 16x16x32. 12 KB LDS.
// 640-960 blocks -> 2.5-3.7 blocks/CU. XCD swizzle: j=id&7 -> XCD;
// bx=(t/nby)*8+j so one XCD owns a contiguous 1/8 slice of A rows.
// ---------------------------------------------------------------------------
__global__ __launch_bounds__(256) void k_mgemm(
    const ushort_t* __restrict__ A, int lda,
    const ushort_t* __restrict__ Bt, int ldb,
    int M, int K, int N, int nbx, int nby,
    ushort_t* __restrict__ outB)
{
    __shared__ ushort_t As[64 * 32];
    __shared__ ushort_t Bs[128 * 32];

    int id = blockIdx.x;
    int j = id & 7, t = id >> 3;
    int by = t % nby;
    int bx = (t / nby) * 8 + j;
    if (bx >= nbx) return;

    const int tid  = threadIdx.x;
    const int w    = tid >> 6;
    const int lane = tid & 63;
    const int l15  = lane & 15;
    const int quad = lane >> 4;
    const int bm = bx * 64, bn = by * 128;
    const int wm = (w & 1) * 32;
    const int wn = (w >> 1) * 64;

    const int sr = lane >> 2;           // 0..15
    const int sc = (lane & 3) * 8;      // 0,8,16,24
    // A: wave w stages rows w*16 .. +15 (1 inst)
    int arow = min(bm + w * 16 + sr, M - 1);
    const ushort_t* ag = A + (size_t)arow * lda + sc;
    ushort_t* al = As + (w * 16 + sr) * 32 + sc;
    // B: wave w stages rows w*32 .. +31 (2 insts)
    const ushort_t* bg0 = Bt + (size_t)(bn + w * 32 + sr) * ldb + sc;
    const ushort_t* bg1 = bg0 + (size_t)16 * ldb;
    ushort_t* bl0 = Bs + (w * 32 + sr) * 32 + sc;
    ushort_t* bl1 = bl0 + 16 * 32;

    f32x4 acc[2][4] = {};

    for (int k0 = 0; k0 < K; k0 += 32) {
        __syncthreads();
        gld_lds16(ag + k0, al);
        gld_lds16(bg0 + k0, bl0);
        gld_lds16(bg1 + k0, bl1);
        __syncthreads();
        bf16x8 af[2], bfr[4];
#pragma unroll
        for (int i = 0; i < 2; ++i)
            af[i] = *(const bf16x8*)(As + (wm + i * 16 + l15) * 32 + quad * 8);
#pragma unroll
        for (int jj = 0; jj < 4; ++jj)
            bfr[jj] = *(const bf16x8*)(Bs + (wn + jj * 16 + l15) * 32 + quad * 8);
#pragma unroll
        for (int i = 0; i < 2; ++i)
#pragma unroll
            for (int jj = 0; jj < 4; ++jj)
                acc[i][jj] = __builtin_amdgcn_mfma_f32_16x16x32_bf16(af[i], bfr[jj], acc[i][jj], 0, 0, 0);
    }

    // C/D layout: col = lane&15, row = quad*4 + reg (m89-verified)
#pragma unroll
    for (int i = 0; i < 2; ++i) {
        int rowb = bm + wm + i * 16 + quad * 4;
#pragma unroll
        for (int jj = 0; jj < 4; ++jj) {
            int col = bn + wn + jj * 16 + l15;
#pragma unroll
            for (int r = 0; r < 4; ++r) {
                int rr = rowb + r;
                if (rr < M)
                    outB[(size_t)rr * N + col] = f2bf(acc[i][jj][r]);
            }
        }
    }
}

// ---------------------------------------------------------------------------
// XCD-feature-sliced aggregation. R3 change: 16 features per lane (was 8):
// each lane loads 2x uint4 (32B) per edge row; slice width = 128 feats,
// NSL = width/128 slices (GCN 4, Cheb 2). Per edge-quad the wave now has 8
// outstanding loads (deeper MLP), gather rounds per node halve, er[]
// broadcast re-reads halve. Per-XCD slice set = 10000*256B = 2.56MB + recs
// 1.28MB < 4MB L2. Trade: VGPR ~60 -> ~90 (occupancy 24 -> ~16 waves/CU).
// Block 256 thr = 32 consecutive nodes x 8 lanes (natural order preserved —
// degree-sort variants proven neutral/regressing in earlier rounds).
// z = sA*acc (+d2*h[c] if dinv) (+sB*other[c]) (+bias); out = celu?(z)
// ---------------------------------------------------------------------------
template<int NSL>
__global__ __launch_bounds__(256) void k_sagg(
    const ushort_t* __restrict__ h, int hs, int hoff,
    const int2* __restrict__ er, const int* __restrict__ rp,
    const float* __restrict__ dinv_g,
    const ushort_t* __restrict__ other, int os, int ooff, float sB,
    const float* __restrict__ bias, float sA,
    ushort_t* __restrict__ outB, float* __restrict__ outF, int outs, int celu)
{
    const int id  = blockIdx.x;
    const int sl  = id % NSL;
    const int tid = threadIdx.x;
    const int c   = (id / NSL) * 32 + (tid >> 3);
    if (c >= N_NODES) return;
    const int f = sl * 128 + ((tid & 7) << 4);
    const ushort_t* hp = h + hoff + f;

    float acc[16] = {0.f, 0.f, 0.f, 0.f, 0.f, 0.f, 0.f, 0.f,
                     0.f, 0.f, 0.f, 0.f, 0.f, 0.f, 0.f, 0.f};
    int e = rp[c];
    const int e1 = rp[c + 1];
    for (; e + 4 <= e1; e += 4) {
        int2 p0 = er[e], p1 = er[e + 1], p2 = er[e + 2], p3 = er[e + 3];
        const ushort_t* r0 = hp + (size_t)p0.x * hs;
        const ushort_t* r1 = hp + (size_t)p1.x * hs;
        const ushort_t* r2 = hp + (size_t)p2.x * hs;
        const ushort_t* r3 = hp + (size_t)p3.x * hs;
        uint4 a0 = *(const uint4*)r0, b0 = *(const uint4*)(r0 + 8);
        uint4 a1 = *(const uint4*)r1, b1 = *(const uint4*)(r1 + 8);
        uint4 a2 = *(const uint4*)r2, b2 = *(const uint4*)(r2 + 8);
        uint4 a3 = *(const uint4*)r3, b3 = *(const uint4*)(r3 + 8);
        float n0 = __int_as_float(p0.y), n1 = __int_as_float(p1.y);
        float n2 = __int_as_float(p2.y), n3 = __int_as_float(p3.y);
        float v[8];
        bf2f8(a0, v);
#pragma unroll
        for (int i = 0; i < 8; ++i) acc[i] = fmaf(n0, v[i], acc[i]);
        bf2f8(b0, v);
#pragma unroll
        for (int i = 0; i < 8; ++i) acc[8 + i] = fmaf(n0, v[i], acc[8 + i]);
        bf2f8(a1, v);
#pragma unroll
        for (int i = 0; i < 8; ++i) acc[i] = fmaf(n1, v[i], acc[i]);
        bf2f8(b1, v);
#pragma unroll
        for (int i = 0; i < 8; ++i) acc[8 + i] = fmaf(n1, v[i], acc[8 + i]);
        bf2f8(a2, v);
#pragma unroll
        for (int i = 0; i < 8; ++i) acc[i] = fmaf(n2, v[i], acc[i]);
        bf2f8(b2, v);
#pragma unroll
        for (int i = 0; i < 8; ++i) acc[8 + i] = fmaf(n2, v[i], acc[8 + i]);
        bf2f8(a3, v);
#pragma unroll
        for (int i = 0; i < 8; ++i) acc[i] = fmaf(n3, v[i], acc[i]);
        bf2f8(b3, v);
#pragma unroll
        for (int i = 0; i < 8; ++i) acc[8 + i] = fmaf(n3, v[i], acc[8 + i]);
    }
    for (; e < e1; ++e) {
        int2 p = er[e];
        const ushort_t* r0 = hp + (size_t)p.x * hs;
        uint4 a = *(const uint4*)r0, b = *(const uint4*)(r0 + 8);
        float nv = __int_as_float(p.y);
        float v[8];
        bf2f8(a, v);
#pragma unroll
        for (int i = 0; i < 8; ++i) acc[i] = fmaf(nv, v[i], acc[i]);
        bf2f8(b, v);
#pragma unroll
        for (int i = 0; i < 8; ++i) acc[8 + i] = fmaf(nv, v[i], acc[8 + i]);
    }

    if (dinv_g) {                       // GCN self-loop term
        float dv = dinv_g[c];
        float d2 = dv * dv;
        const ushort_t* r0 = hp + (size_t)c * hs;
        uint4 a = *(const uint4*)r0, b = *(const uint4*)(r0 + 8);
        float v[8];
        bf2f8(a, v);
#pragma unroll
        for (int i = 0; i < 8; ++i) acc[i] = fmaf(d2, v[i], acc[i]);
        bf2f8(b, v);
#pragma unroll
        for (int i = 0; i < 8; ++i) acc[8 + i] = fmaf(d2, v[i], acc[8 + i]);
    }
    float r[16];
#pragma unroll
    for (int i = 0; i < 16; ++i) r[i] = sA * acc[i];
    if (other) {
        const ushort_t* op = other + (size_t)c * os + ooff + f;
        uint4 a = *(const uint4*)op, b = *(const uint4*)(op + 8);
        float o[8];
        bf2f8(a, o);
#pragma unroll
        for (int i = 0; i < 8; ++i) r[i] = fmaf(sB, o[i], r[i]);
        bf2f8(b, o);
#pragma unroll
        for (int i = 0; i < 8; ++i) r[8 + i] = fmaf(sB, o[i], r[8 + i]);
    }
    if (bias) {
#pragma unroll
        for (int i = 0; i < 16; ++i) r[i] += bias[f + i];
    }
    if (celu) {
#pragma unroll
        for (int i = 0; i < 16; ++i) r[i] = r[i] > 0.f ? r[i] : expm1f(r[i]);
    }
    if (outF) {
        float* op = outF + (size_t)c * outs + f;
        *(float4*)op        = make_float4(r[0],  r[1],  r[2],  r[3]);
        *(float4*)(op + 4)  = make_float4(r[4],  r[5],  r[6],  r[7]);
        *(float4*)(op + 8)  = make_float4(r[8],  r[9],  r[10], r[11]);
        *(float4*)(op + 12) = make_float4(r[12], r[13], r[14], r[15]);
    } else {
        ushort_t* ob = outB + (size_t)c * outs + f;
        *(uint4*)ob       = f2bf8v(r);
        *(uint4*)(ob + 8) = f2bf8v(r + 8);
    }
}

// ---------------------------------------------------------------------------

extern "C" void kernel_launch(void* const* d_in, const int* in_sizes, int n_in,
                              void* d_out, int out_size, void* d_ws, size_t ws_size,
                              hipStream_t stream) {
    const float* x  = (const float*)d_in[0];
    const int*   ei = (const int*)d_in[1];
    const float* ew = (const float*)d_in[2];
    const float* W1 = (const float*)d_in[3];
    const float* b1 = (const float*)d_in[4];
    const float* W2 = (const float*)d_in[5];
    const float* b2 = (const float*)d_in[6];
    const float* Wc = (const float*)d_in[7];
    const float* bc = (const float*)d_in[8];
    float* out = (float*)d_out;

    const int* row = ei;
    const int* col = ei + N_EDGES;

    char* ws = (char*)d_ws;
    size_t off = 0;
    auto alloc = [&](size_t bytes) -> void* {
        void* p = ws + off;
        off += (bytes + 255) & ~(size_t)255;
        return p;
    };
    ushort_t* xb    = (ushort_t*)alloc((size_t)N_NODES * FDIM * 2);
    ushort_t* bufA  = (ushort_t*)alloc((size_t)N_NODES * FDIM * 2);   // h1 / h2
    ushort_t* bufB  = (ushort_t*)alloc((size_t)N_NODES * FDIM * 2);   // h1a / T0
    ushort_t* Y     = (ushort_t*)alloc((size_t)N_NODES * NCAT * 2);   // [Y0|Y1|Y2]
    ushort_t* P     = (ushort_t*)alloc((size_t)N_NODES * DOUT * 2);
    ushort_t* W1t   = (ushort_t*)alloc((size_t)FDIM * FDIM * 2);
    ushort_t* W2t   = (ushort_t*)alloc((size_t)FDIM * FDIM * 2);
    ushort_t* Wcatt = (ushort_t*)alloc((size_t)NCAT * FDIM * 2);
    size_t zs = off;
    float* deg_g  = (float*)alloc((size_t)N_NODES * 4);
    float* deg_c  = (float*)alloc((size_t)N_NODES * 4);
    int*   counts = (int*)alloc((size_t)N_NODES * 4);
    int*   fillb  = (int*)alloc((size_t)N_NODES * 4);
    size_t ze = off;
    float* dinv_g = (float*)alloc((size_t)N_NODES * 4);
    float* dinv_c = (float*)alloc((size_t)N_NODES * 4);
    int*   rp     = (int*)alloc((size_t)(N_NODES + 1) * 4);
    int*   part   = (int*)alloc(64 * 4);
    int2*  eg     = (int2*)alloc((size_t)N_EDGES * 8);
    int2*  ec     = (int2*)alloc((size_t)N_EDGES * 8);

    const int TB = 256;
    dim3 edgeGrid((N_EDGES + TB - 1) / TB);
    int nScanB = (N_NODES + 255) / 256;     // 40

    // ---- preprocessing + conversions ----
    hipMemsetAsync(ws + zs, 0, ze - zs, stream);
    k_pre1<<<EDGE_BLOCKS + XB_BLOCKS + 224, 256, 0, stream>>>(
        row, col, ew, deg_g, deg_c, counts,
        x, xb, W1, W1t, W2, W2t, Wc, Wcatt);
    k_dinv_scan1<<<nScanB, 256, 0, stream>>>(deg_g, deg_c, dinv_g, dinv_c, counts, rp, part, N_NODES);
    k_scan23<<<nScanB, 256, 0, stream>>>(rp, part, nScanB, N_NODES);
    k_fill<<<edgeGrid, TB, 0, stream>>>(row, col, ew, dinv_g, dinv_c, rp, fillb, eg, ec, N_EDGES);

    auto mgemm = [&](const ushort_t* A, const ushort_t* Bt, int N, ushort_t* oB) {
        int nbx = (N_NODES + 63) / 64, nby = N / 128;   // 157, {4,6}
        int G = 8 * (((nbx + 7) / 8) * nby);            // 640 / 960
        k_mgemm<<<G, 256, 0, stream>>>(A, FDIM, Bt, FDIM, N_NODES, FDIM, N, nbx, nby, oB);
    };
    int gG = ((N_NODES + 31) / 32) * 4;     // 313*4  (GCN: 512 = 4 x 128)
    int gC = ((N_NODES + 31) / 32) * 2;     // 313*2  (Cheb: 256 = 2 x 128)

    // ---- GCN layer 1: h1 = x@W1; h1a = celu(agg(h1)+b1) ----
    mgemm(xb, W1t, FDIM, bufA);
    k_sagg<4><<<gG, 256, 0, stream>>>(bufA, FDIM, 0, eg, rp, dinv_g,
                                      (const ushort_t*)nullptr, 0, 0, 0.f,
                                      b1, 1.f, bufB, (float*)nullptr, FDIM, 1);
    // ---- GCN layer 2 ----
    mgemm(bufB, W2t, FDIM, bufA);
    k_sagg<4><<<gG, 256, 0, stream>>>(bufA, FDIM, 0, eg, rp, dinv_g,
                                      (const ushort_t*)nullptr, 0, 0, 0.f,
                                      b2, 1.f, bufB, (float*)nullptr, FDIM, 1);
    // ---- Cheb (commuted): Y = T0 @ [W0-W2 | W1 | W2] ----
    mgemm(bufB, Wcatt, NCAT, Y);
    // P = Y1 + 2*Lhat(Y2)
    k_sagg<2><<<gC, 256, 0, stream>>>(Y, NCAT, 2 * DOUT, ec, rp,
                                      (const float*)nullptr,
                                      Y, NCAT, DOUT, 1.f,
                                      (const float*)nullptr, 2.f,
                                      P, (float*)nullptr, DOUT, 0);
    // out = celu(Y0 + Lhat(P) + bc)   (fp32 straight to d_out)
    k_sagg<2><<<gC, 256, 0, stream>>>(P, DOUT, 0, ec, rp,
                                      (const float*)nullptr,
                                      Y, NCAT, 0, 1.f,
                                      bc, 1.f,
                                      (ushort_t*)nullptr, out, DOUT, 1);
}

// Round 4
// 246.816 us; speedup vs baseline: 3.5329x; 1.0217x over previous
//
#include <hip/hip_runtime.h>
#include <math.h>

#define N_NODES 10000
#define N_EDGES 160000
#define FDIM    512
#define DOUT    256
#define NCAT    768     // [W0-W2 | W1 | W2]

typedef unsigned short ushort_t;
typedef unsigned int   uint_t;
typedef __attribute__((ext_vector_type(8))) short bf16x8;
typedef __attribute__((ext_vector_type(4))) float f32x4;

// ---------------------------------------------------------------------------
// helpers
// ---------------------------------------------------------------------------
__device__ inline ushort_t f2bf(float f) {
    uint_t u = __float_as_uint(f);
    u += 0x7fffu + ((u >> 16) & 1u);        // round-to-nearest-even
    return (ushort_t)(u >> 16);
}
__device__ inline void bf2f8(uint4 u, float* v) {
    v[0] = __uint_as_float(u.x << 16); v[1] = __uint_as_float(u.x & 0xffff0000u);
    v[2] = __uint_as_float(u.y << 16); v[3] = __uint_as_float(u.y & 0xffff0000u);
    v[4] = __uint_as_float(u.z << 16); v[5] = __uint_as_float(u.z & 0xffff0000u);
    v[6] = __uint_as_float(u.w << 16); v[7] = __uint_as_float(u.w & 0xffff0000u);
}
__device__ inline uint4 f2bf8v(const float* v) {
    uint4 u;
    u.x = (uint_t)f2bf(v[0]) | ((uint_t)f2bf(v[1]) << 16);
    u.y = (uint_t)f2bf(v[2]) | ((uint_t)f2bf(v[3]) << 16);
    u.z = (uint_t)f2bf(v[4]) | ((uint_t)f2bf(v[5]) << 16);
    u.w = (uint_t)f2bf(v[6]) | ((uint_t)f2bf(v[7]) << 16);
    return u;
}
__device__ inline void gld_lds16(const ushort_t* g, ushort_t* l) {
    __builtin_amdgcn_global_load_lds(
        (const __attribute__((address_space(1))) unsigned int*)g,
        (__attribute__((address_space(3))) unsigned int*)l,
        16, 0, 0);
}

// ---------------------------------------------------------------------------
// Merged preprocessing stage 1 + conversions (unchanged from 240us baseline).
// ---------------------------------------------------------------------------
#define EDGE_BLOCKS 625   // 160000 / 256
#define XB_BLOCKS   5000  // 10000*512 / 4 / 256
#define FILL_BLOCKS 625
#define G_GEMM1     640   // 8*ceil(157/8)*4

__global__ __launch_bounds__(256) void k_pre1(
    const int* __restrict__ row, const int* __restrict__ col,
    const float* __restrict__ w,
    float* deg_g, float* deg_c, int* counts,
    const float* __restrict__ x,  ushort_t* __restrict__ xb,
    const float* __restrict__ W1, ushort_t* __restrict__ W1t,
    const float* __restrict__ W2, ushort_t* __restrict__ W2t,
    const float* __restrict__ Wc, ushort_t* __restrict__ Wcatt)
{
    __shared__ float tile[64][65];
    int b = blockIdx.x;
    int tid = threadIdx.x;
    if (b < EDGE_BLOCKS) {
        int e = b * 256 + tid;
        if (e < N_EDGES) {
            int r = row[e], c = col[e];
            float wv = w[e];
            atomicAdd(&deg_g[c], wv);
            if (r != c) atomicAdd(&deg_c[r], wv);
            atomicAdd(&counts[c], 1);
        }
        return;
    }
    b -= EDGE_BLOCKS;
    if (b < XB_BLOCKS) {
        int t = b * 256 + tid;
        float4 v = *(const float4*)(x + (size_t)t * 4);
        uint2 p;
        p.x = (uint_t)f2bf(v.x) | ((uint_t)f2bf(v.y) << 16);
        p.y = (uint_t)f2bf(v.z) | ((uint_t)f2bf(v.w) << 16);
        *(uint2*)(xb + (size_t)t * 4) = p;
        return;
    }
    b -= XB_BLOCKS;
    const float* src; const float* src2 = nullptr;
    ushort_t* dst; int kt, ntG, srcld;
    if (b < 64) {                       // W1 [512][512]
        kt = b >> 3; ntG = b & 7; srcld = FDIM;
        src = W1 + (size_t)(kt * 64) * FDIM + ntG * 64;
        dst = W1t;
    } else if (b < 128) {               // W2
        int bb = b - 64;
        kt = bb >> 3; ntG = bb & 7; srcld = FDIM;
        src = W2 + (size_t)(kt * 64) * FDIM + ntG * 64;
        dst = W2t;
    } else {                            // Wcat: ntG in [0,12), kt in [0,8)
        int bb = b - 128;
        ntG = bb / 8; kt = bb % 8; srcld = DOUT;
        int s = ntG >> 2;               // section 0,1,2
        int nl = (ntG & 3) * 64;        // col within 256
        if (s == 0) {                   // W0 - W2
            src  = Wc + (size_t)(kt * 64) * DOUT + nl;
            src2 = Wc + (size_t)2 * FDIM * DOUT + (size_t)(kt * 64) * DOUT + nl;
        } else if (s == 1) {            // W1 (Cheb k=1)
            src  = Wc + (size_t)1 * FDIM * DOUT + (size_t)(kt * 64) * DOUT + nl;
        } else {                        // W2
            src  = Wc + (size_t)2 * FDIM * DOUT + (size_t)(kt * 64) * DOUT + nl;
        }
        dst = Wcatt;
    }
    // load phase: thread (r = tid>>2, c0 = (tid&3)*16) loads 16 floats
    {
        int r = tid >> 2, c0 = (tid & 3) * 16;
        const float* sp = src + (size_t)r * srcld + c0;
#pragma unroll
        for (int q = 0; q < 4; ++q) {
            float4 a = *(const float4*)(sp + q * 4);
            if (src2) {
                float4 bsub = *(const float4*)(src2 + (size_t)r * srcld + c0 + q * 4);
                a.x -= bsub.x; a.y -= bsub.y; a.z -= bsub.z; a.w -= bsub.w;
            }
            tile[r][c0 + q * 4 + 0] = a.x;
            tile[r][c0 + q * 4 + 1] = a.y;
            tile[r][c0 + q * 4 + 2] = a.z;
            tile[r][c0 + q * 4 + 3] = a.w;
        }
    }
    __syncthreads();
    // store phase: thread (n = tid>>2, k0 = (tid&3)*16) writes 16 bf16 (32 B)
    {
        int n = tid >> 2, k0 = (tid & 3) * 16;
        float v[16];
#pragma unroll
        for (int i = 0; i < 16; ++i) v[i] = tile[k0 + i][n];
        uint4 u0 = f2bf8v(v);
        uint4 u1 = f2bf8v(v + 8);
        ushort_t* dp = dst + (size_t)(ntG * 64 + n) * FDIM + kt * 64 + k0;
        *(uint4*)dp = u0;
        *(uint4*)(dp + 8) = u1;
    }
}

// ---------------------------------------------------------------------------
// R4: single-block full scan (replaces k_dinv_scan1 + k_scan23).
// 1024 threads x 10 contiguous elements; per-thread serial scan, then
// wave-shfl inclusive scan of thread sums, then 16 wave partials scanned by
// wave 0. dinv_g/dinv_c computed in the same pass. ~240 KB traffic from one
// CU (~3-4 us) but removes one dispatch boundary and one kernel ramp.
// ---------------------------------------------------------------------------
__global__ __launch_bounds__(1024) void k_scanfull(
    const float* __restrict__ deg_g, const float* __restrict__ deg_c,
    float* __restrict__ dinv_g, float* __restrict__ dinv_c,
    const int* __restrict__ counts, int* __restrict__ rp)
{
    __shared__ int wsum[16];
    const int tid  = threadIdx.x;           // 0..1023
    const int base = tid * 10;
    int loc[10]; int sum = 0;
#pragma unroll
    for (int j = 0; j < 10; ++j) {
        int i = base + j;
        int v = (i < N_NODES) ? counts[i] : 0;
        loc[j] = sum; sum += v;
        if (i < N_NODES) {
            dinv_g[i] = rsqrtf(deg_g[i] + 1.0f);
            float d = deg_c[i];
            dinv_c[i] = d > 0.f ? rsqrtf(d) : 0.f;
        }
    }
    const int lane = tid & 63, wid = tid >> 6;
    int x = sum;
    for (int o = 1; o < 64; o <<= 1) {      // inclusive wave scan
        int y = __shfl_up(x, o, 64);
        if (lane >= o) x += y;
    }
    if (lane == 63) wsum[wid] = x;
    __syncthreads();
    if (wid == 0) {
        int v = (lane < 16) ? wsum[lane] : 0;
        int y = v;
        for (int o = 1; o < 16; o <<= 1) {
            int z = __shfl_up(y, o, 64);
            if (lane >= o) y += z;
        }
        if (lane < 16) wsum[lane] = y - v;  // exclusive wave offsets
    }
    __syncthreads();
    const int off = wsum[wid] + (x - sum);  // exclusive prefix for this thread
#pragma unroll
    for (int j = 0; j < 10; ++j) {
        int i = base + j;
        if (i <= N_NODES) rp[i] = off + loc[j];   // includes rp[N_NODES]=E
    }
}

// ---------------------------------------------------------------------------
// R4: fused CSR-fill + GCN-layer-1 GEMM (block-range split). Blocks
// [0,625): edge fill (4B records scatter; ~4us, hides under the GEMM).
// Blocks [625,1265): the m97-structure 64x128 GEMM h1 = xb @ W1t.
// Inputs of both halves are ready after k_scanfull; outputs disjoint.
// XCD swizzle unchanged: vb = id-625, constant offset keeps mod-8 classes.
// ---------------------------------------------------------------------------
__global__ __launch_bounds__(256) void k_fillgemm(
    const int* __restrict__ row, const int* __restrict__ col,
    const float* __restrict__ w,
    const float* __restrict__ dinv_g, const float* __restrict__ dinv_c,
    const int* __restrict__ rp, int* __restrict__ fillb,
    int2* __restrict__ eg, int2* __restrict__ ec,
    const ushort_t* __restrict__ A, const ushort_t* __restrict__ Bt,
    ushort_t* __restrict__ outB)
{
    __shared__ ushort_t As[64 * 32];
    __shared__ ushort_t Bs[128 * 32];
    const int tid = threadIdx.x;
    int id = blockIdx.x;

    if (id < FILL_BLOCKS) {                 // ---- CSR fill ----
        int e = id * 256 + tid;
        if (e >= N_EDGES) return;
        int r = row[e], c = col[e];
        float wv = w[e];
        float ng = dinv_g[r] * wv * dinv_g[c];
        float w0 = (r == c) ? 0.f : wv;
        float nc = -(dinv_c[r] * w0 * dinv_c[c]);
        int pos = rp[c] + atomicAdd(&fillb[c], 1);
        eg[pos] = make_int2(r, __float_as_int(ng));
        ec[pos] = make_int2(r, __float_as_int(nc));
        return;
    }

    // ---- GEMM: h1 = xb @ W1t, M=10000, N=K=512, nbx=157, nby=4 ----
    int vb = id - FILL_BLOCKS;
    int j = vb & 7, t = vb >> 3;
    int by = t % 4;
    int bx = (t / 4) * 8 + j;
    if (bx >= 157) return;

    const int w4   = tid >> 6;
    const int lane = tid & 63;
    const int l15  = lane & 15;
    const int quad = lane >> 4;
    const int bm = bx * 64, bn = by * 128;
    const int wm = (w4 & 1) * 32;
    const int wn = (w4 >> 1) * 64;

    const int sr = lane >> 2;
    const int sc = (lane & 3) * 8;
    int arow = min(bm + w4 * 16 + sr, N_NODES - 1);
    const ushort_t* ag = A + (size_t)arow * FDIM + sc;
    ushort_t* al = As + (w4 * 16 + sr) * 32 + sc;
    const ushort_t* bg0 = Bt + (size_t)(bn + w4 * 32 + sr) * FDIM + sc;
    const ushort_t* bg1 = bg0 + (size_t)16 * FDIM;
    ushort_t* bl0 = Bs + (w4 * 32 + sr) * 32 + sc;
    ushort_t* bl1 = bl0 + 16 * 32;

    f32x4 acc[2][4] = {};

    for (int k0 = 0; k0 < FDIM; k0 += 32) {
        __syncthreads();
        gld_lds16(ag + k0, al);
        gld_lds16(bg0 + k0, bl0);
        gld_lds16(bg1 + k0, bl1);
        __syncthreads();
        bf16x8 af[2], bfr[4];
#pragma unroll
        for (int i = 0; i < 2; ++i)
            af[i] = *(const bf16x8*)(As + (wm + i * 16 + l15) * 32 + quad * 8);
#pragma unroll
        for (int jj = 0; jj < 4; ++jj)
            bfr[jj] = *(const bf16x8*)(Bs + (wn + jj * 16 + l15) * 32 + quad * 8);
#pragma unroll
        for (int i = 0; i < 2; ++i)
#pragma unroll
            for (int jj = 0; jj < 4; ++jj)
                acc[i][jj] = __builtin_amdgcn_mfma_f32_16x16x32_bf16(af[i], bfr[jj], acc[i][jj], 0, 0, 0);
    }
#pragma unroll
    for (int i = 0; i < 2; ++i) {
        int rowb = bm + wm + i * 16 + quad * 4;
#pragma unroll
        for (int jj = 0; jj < 4; ++jj) {
            int colc = bn + wn + jj * 16 + l15;
#pragma unroll
            for (int r = 0; r < 4; ++r) {
                int rr = rowb + r;
                if (rr < N_NODES)
                    outB[(size_t)rr * FDIM + colc] = f2bf(acc[i][jj][r]);
            }
        }
    }
}

// ---------------------------------------------------------------------------
// Staged bf16 MFMA GEMM (m97 structure), unchanged 240us-baseline kernel.
// ---------------------------------------------------------------------------
__global__ __launch_bounds__(256) void k_mgemm(
    const ushort_t* __restrict__ A, int lda,
    const ushort_t* __restrict__ Bt, int ldb,
    int M, int K, int N, int nbx, int nby,
    ushort_t* __restrict__ outB)
{
    __shared__ ushort_t As[64 * 32];
    __shared__ ushort_t Bs[128 * 32];

    int id = blockIdx.x;
    int j = id & 7, t = id >> 3;
    int by = t % nby;
    int bx = (t / nby) * 8 + j;
    if (bx >= nbx) return;

    const int tid  = threadIdx.x;
    const int w    = tid >> 6;
    const int lane = tid & 63;
    const int l15  = lane & 15;
    const int quad = lane >> 4;
    const int bm = bx * 64, bn = by * 128;
    const int wm = (w & 1) * 32;
    const int wn = (w >> 1) * 64;

    const int sr = lane >> 2;           // 0..15
    const int sc = (lane & 3) * 8;      // 0,8,16,24
    int arow = min(bm + w * 16 + sr, M - 1);
    const ushort_t* ag = A + (size_t)arow * lda + sc;
    ushort_t* al = As + (w * 16 + sr) * 32 + sc;
    const ushort_t* bg0 = Bt + (size_t)(bn + w * 32 + sr) * ldb + sc;
    const ushort_t* bg1 = bg0 + (size_t)16 * ldb;
    ushort_t* bl0 = Bs + (w * 32 + sr) * 32 + sc;
    ushort_t* bl1 = bl0 + 16 * 32;

    f32x4 acc[2][4] = {};

    for (int k0 = 0; k0 < K; k0 += 32) {
        __syncthreads();
        gld_lds16(ag + k0, al);
        gld_lds16(bg0 + k0, bl0);
        gld_lds16(bg1 + k0, bl1);
        __syncthreads();
        bf16x8 af[2], bfr[4];
#pragma unroll
        for (int i = 0; i < 2; ++i)
            af[i] = *(const bf16x8*)(As + (wm + i * 16 + l15) * 32 + quad * 8);
#pragma unroll
        for (int jj = 0; jj < 4; ++jj)
            bfr[jj] = *(const bf16x8*)(Bs + (wn + jj * 16 + l15) * 32 + quad * 8);
#pragma unroll
        for (int i = 0; i < 2; ++i)
#pragma unroll
            for (int jj = 0; jj < 4; ++jj)
                acc[i][jj] = __builtin_amdgcn_mfma_f32_16x16x32_bf16(af[i], bfr[jj], acc[i][jj], 0, 0, 0);
    }

    // C/D layout: col = lane&15, row = quad*4 + reg (m89-verified)
#pragma unroll
    for (int i = 0; i < 2; ++i) {
        int rowb = bm + wm + i * 16 + quad * 4;
#pragma unroll
        for (int jj = 0; jj < 4; ++jj) {
            int col = bn + wn + jj * 16 + l15;
#pragma unroll
            for (int r = 0; r < 4; ++r) {
                int rr = rowb + r;
                if (rr < M)
                    outB[(size_t)rr * N + col] = f2bf(acc[i][jj][r]);
            }
        }
    }
}

// ---------------------------------------------------------------------------
// XCD-feature-sliced aggregation — exact 240us-baseline (R0) kernel.
// SL slices of 64 features; block 256 thr = 32 consecutive nodes x 8 lanes.
// z = sA*acc (+d2*h[c] if dinv) (+sB*other[c]) (+bias); out = celu?(z)
// ---------------------------------------------------------------------------
template<int SL>
__global__ __launch_bounds__(256) void k_sagg(
    const ushort_t* __restrict__ h, int hs, int hoff,
    const int2* __restrict__ er, const int* __restrict__ rp,
    const float* __restrict__ dinv_g,
    const ushort_t* __restrict__ other, int os, int ooff, float sB,
    const float* __restrict__ bias, float sA,
    ushort_t* __restrict__ outB, float* __restrict__ outF, int outs, int celu)
{
    const int id  = blockIdx.x;
    const int sl  = id % SL;
    const int tid = threadIdx.x;
    const int c   = (id / SL) * 32 + (tid >> 3);
    if (c >= N_NODES) return;
    const int f = sl * 64 + ((tid & 7) << 3);
    const ushort_t* hp = h + hoff + f;

    float acc[8] = {0.f, 0.f, 0.f, 0.f, 0.f, 0.f, 0.f, 0.f};
    int e = rp[c];
    const int e1 = rp[c + 1];
    for (; e + 4 <= e1; e += 4) {
        int2 p0 = er[e], p1 = er[e + 1], p2 = er[e + 2], p3 = er[e + 3];
        uint4 u0 = *(const uint4*)(hp + (size_t)p0.x * hs);
        uint4 u1 = *(const uint4*)(hp + (size_t)p1.x * hs);
        uint4 u2 = *(const uint4*)(hp + (size_t)p2.x * hs);
        uint4 u3 = *(const uint4*)(hp + (size_t)p3.x * hs);
        float n0 = __int_as_float(p0.y), n1 = __int_as_float(p1.y);
        float n2 = __int_as_float(p2.y), n3 = __int_as_float(p3.y);
        float v0[8], v1[8], v2[8], v3[8];
        bf2f8(u0, v0); bf2f8(u1, v1); bf2f8(u2, v2); bf2f8(u3, v3);
#pragma unroll
        for (int i = 0; i < 8; ++i) {
            acc[i] = fmaf(n0, v0[i], acc[i]);
            acc[i] = fmaf(n1, v1[i], acc[i]);
            acc[i] = fmaf(n2, v2[i], acc[i]);
            acc[i] = fmaf(n3, v3[i], acc[i]);
        }
    }
    for (; e < e1; ++e) {
        int2 p = er[e];
        uint4 u = *(const uint4*)(hp + (size_t)p.x * hs);
        float nv = __int_as_float(p.y);
        float v[8]; bf2f8(u, v);
#pragma unroll
        for (int i = 0; i < 8; ++i) acc[i] = fmaf(nv, v[i], acc[i]);
    }

    if (dinv_g) {                       // GCN self-loop term
        float dv = dinv_g[c];
        float d2 = dv * dv;
        uint4 u = *(const uint4*)(hp + (size_t)c * hs);
        float v[8]; bf2f8(u, v);
#pragma unroll
        for (int i = 0; i < 8; ++i) acc[i] = fmaf(d2, v[i], acc[i]);
    }
    float r[8];
#pragma unroll
    for (int i = 0; i < 8; ++i) r[i] = sA * acc[i];
    if (other) {
        uint4 u = *(const uint4*)(other + (size_t)c * os + ooff + f);
        float o[8]; bf2f8(u, o);
#pragma unroll
        for (int i = 0; i < 8; ++i) r[i] = fmaf(sB, o[i], r[i]);
    }
    if (bias) {
#pragma unroll
        for (int i = 0; i < 8; ++i) r[i] += bias[f + i];
    }
    if (celu) {
#pragma unroll
        for (int i = 0; i < 8; ++i) r[i] = r[i] > 0.f ? r[i] : expm1f(r[i]);
    }
    if (outF) {
        float* op = outF + (size_t)c * outs + f;
        *(float4*)op       = make_float4(r[0], r[1], r[2], r[3]);
        *(float4*)(op + 4) = make_float4(r[4], r[5], r[6], r[7]);
    } else {
        *(uint4*)(outB + (size_t)c * outs + f) = f2bf8v(r);
    }
}

// ---------------------------------------------------------------------------

extern "C" void kernel_launch(void* const* d_in, const int* in_sizes, int n_in,
                              void* d_out, int out_size, void* d_ws, size_t ws_size,
                              hipStream_t stream) {
    const float* x  = (const float*)d_in[0];
    const int*   ei = (const int*)d_in[1];
    const float* ew = (const float*)d_in[2];
    const float* W1 = (const float*)d_in[3];
    const float* b1 = (const float*)d_in[4];
    const float* W2 = (const float*)d_in[5];
    const float* b2 = (const float*)d_in[6];
    const float* Wc = (const float*)d_in[7];
    const float* bc = (const float*)d_in[8];
    float* out = (float*)d_out;

    const int* row = ei;
    const int* col = ei + N_EDGES;

    char* ws = (char*)d_ws;
    size_t off = 0;
    auto alloc = [&](size_t bytes) -> void* {
        void* p = ws + off;
        off += (bytes + 255) & ~(size_t)255;
        return p;
    };
    ushort_t* xb    = (ushort_t*)alloc((size_t)N_NODES * FDIM * 2);
    ushort_t* bufA  = (ushort_t*)alloc((size_t)N_NODES * FDIM * 2);   // h1 / h2
    ushort_t* bufB  = (ushort_t*)alloc((size_t)N_NODES * FDIM * 2);   // h1a / T0
    ushort_t* Y     = (ushort_t*)alloc((size_t)N_NODES * NCAT * 2);   // [Y0|Y1|Y2]
    ushort_t* P     = (ushort_t*)alloc((size_t)N_NODES * DOUT * 2);
    ushort_t* W1t   = (ushort_t*)alloc((size_t)FDIM * FDIM * 2);
    ushort_t* W2t   = (ushort_t*)alloc((size_t)FDIM * FDIM * 2);
    ushort_t* Wcatt = (ushort_t*)alloc((size_t)NCAT * FDIM * 2);
    size_t zs = off;
    float* deg_g  = (float*)alloc((size_t)N_NODES * 4);
    float* deg_c  = (float*)alloc((size_t)N_NODES * 4);
    int*   counts = (int*)alloc((size_t)N_NODES * 4);
    int*   fillb  = (int*)alloc((size_t)N_NODES * 4);
    size_t ze = off;
    float* dinv_g = (float*)alloc((size_t)N_NODES * 4);
    float* dinv_c = (float*)alloc((size_t)N_NODES * 4);
    int*   rp     = (int*)alloc((size_t)(N_NODES + 1) * 4);
    int2*  eg     = (int2*)alloc((size_t)N_EDGES * 8);
    int2*  ec     = (int2*)alloc((size_t)N_EDGES * 8);

    // ---- preprocessing + conversions ----
    hipMemsetAsync(ws + zs, 0, ze - zs, stream);
    k_pre1<<<EDGE_BLOCKS + XB_BLOCKS + 224, 256, 0, stream>>>(
        row, col, ew, deg_g, deg_c, counts,
        x, xb, W1, W1t, W2, W2t, Wc, Wcatt);
    k_scanfull<<<1, 1024, 0, stream>>>(deg_g, deg_c, dinv_g, dinv_c, counts, rp);
    // fill + GCN layer-1 GEMM fused (block-range split)
    k_fillgemm<<<FILL_BLOCKS + G_GEMM1, 256, 0, stream>>>(
        row, col, ew, dinv_g, dinv_c, rp, fillb, eg, ec, xb, W1t, bufA);

    auto mgemm = [&](const ushort_t* A, const ushort_t* Bt, int N, ushort_t* oB) {
        int nbx = (N_NODES + 63) / 64, nby = N / 128;   // 157, {4,6}
        int G = 8 * (((nbx + 7) / 8) * nby);            // 640 / 960
        k_mgemm<<<G, 256, 0, stream>>>(A, FDIM, Bt, FDIM, N_NODES, FDIM, N, nbx, nby, oB);
    };
    int g8 = ((N_NODES + 31) / 32) * 8;     // 313*8
    int g4 = ((N_NODES + 31) / 32) * 4;     // 313*4

    // ---- GCN layer 1 aggregation: h1a = celu(agg(h1)+b1) ----
    k_sagg<8><<<g8, 256, 0, stream>>>(bufA, FDIM, 0, eg, rp, dinv_g,
                                      (const ushort_t*)nullptr, 0, 0, 0.f,
                                      b1, 1.f, bufB, (float*)nullptr, FDIM, 1);
    // ---- GCN layer 2 ----
    mgemm(bufB, W2t, FDIM, bufA);
    k_sagg<8><<<g8, 256, 0, stream>>>(bufA, FDIM, 0, eg, rp, dinv_g,
                                      (const ushort_t*)nullptr, 0, 0, 0.f,
                                      b2, 1.f, bufB, (float*)nullptr, FDIM, 1);
    // ---- Cheb (commuted): Y = T0 @ [W0-W2 | W1 | W2] ----
    mgemm(bufB, Wcatt, NCAT, Y);
    // P = Y1 + 2*Lhat(Y2)
    k_sagg<4><<<g4, 256, 0, stream>>>(Y, NCAT, 2 * DOUT, ec, rp,
                                      (const float*)nullptr,
                                      Y, NCAT, DOUT, 1.f,
                                      (const float*)nullptr, 2.f,
                                      P, (float*)nullptr, DOUT, 0);
    // out = celu(Y0 + Lhat(P) + bc)   (fp32 straight to d_out)
    k_sagg<4><<<g4, 256, 0, stream>>>(P, DOUT, 0, ec, rp,
                                      (const float*)nullptr,
                                      Y, NCAT, 0, 1.f,
                                      bc, 1.f,
                                      (ushort_t*)nullptr, out, DOUT, 1);
}